// Round 1
// baseline (1398.740 us; speedup 1.0000x reference)
//
#include <hip/hip_runtime.h>
#include <hip/hip_bf16.h>

#define DIMN 2048
#define RANKN 128
#define TT 1024
#define BBATCH 16
#define BD (BBATCH * DIMN)   // 32768 elements per timestep slice

// ---------------------------------------------------------------------------
// Generic tiled fp32 GEMM:  C[m*ldc + n] = sum_k A[m*lda + k] * Bt[n*ldb + k]
// (B is given transposed, i.e. Bt is [N x K] row-major — matches V_x [R,D]
//  and U_x [D,R] layouts exactly.)
// BM=BN=64, BK=32, 256 threads, 4x4 micro-tile per thread.
// All problem dims here divide the tile sizes evenly — no edge guards.
// ---------------------------------------------------------------------------
__global__ __launch_bounds__(256)
void gemm_abt(const float* __restrict__ A, const float* __restrict__ Bt,
              float* __restrict__ C, int M, int N, int K,
              int lda, int ldb, int ldc) {
    constexpr int BM = 64, BN = 64, BK = 32;
    __shared__ float As[BM][BK + 1];   // +1 pad: conflict-free compute reads
    __shared__ float Bs[BN][BK + 1];

    const int m0 = blockIdx.x * BM;
    const int n0 = blockIdx.y * BN;
    const int tid = threadIdx.x;
    const int tx = tid & 15;       // 0..15 -> n
    const int ty = tid >> 4;       // 0..15 -> m

    float acc[4][4] = {};

    for (int k0 = 0; k0 < K; k0 += BK) {
        // Load tiles: 64x32 floats each = 512 float4s, 256 threads -> 2 each.
        #pragma unroll
        for (int j = 0; j < 2; ++j) {
            int off4 = j * 256 + tid;          // coalesced across threads
            int r = off4 >> 3;                 // 8 float4 per row
            int c = (off4 & 7) * 4;
            float4 va = *(const float4*)(A  + (size_t)(m0 + r) * lda + k0 + c);
            As[r][c + 0] = va.x; As[r][c + 1] = va.y;
            As[r][c + 2] = va.z; As[r][c + 3] = va.w;
            float4 vb = *(const float4*)(Bt + (size_t)(n0 + r) * ldb + k0 + c);
            Bs[r][c + 0] = vb.x; Bs[r][c + 1] = vb.y;
            Bs[r][c + 2] = vb.z; Bs[r][c + 3] = vb.w;
        }
        __syncthreads();

        #pragma unroll
        for (int k = 0; k < BK; ++k) {
            float a[4], b[4];
            #pragma unroll
            for (int i = 0; i < 4; ++i) a[i] = As[ty * 4 + i][k];
            #pragma unroll
            for (int j = 0; j < 4; ++j) b[j] = Bs[tx * 4 + j][k];
            #pragma unroll
            for (int i = 0; i < 4; ++i)
                #pragma unroll
                for (int j = 0; j < 4; ++j)
                    acc[i][j] += a[i] * b[j];
        }
        __syncthreads();
    }

    #pragma unroll
    for (int i = 0; i < 4; ++i) {
        float4 v = make_float4(acc[i][0], acc[i][1], acc[i][2], acc[i][3]);
        *(float4*)(C + (size_t)(m0 + ty * 4 + i) * ldc + n0 + tx * 4) = v;
    }
}

// ---------------------------------------------------------------------------
// Scan: one thread per (b,d) element; sequential loop over t.
// wx[t] was pre-written into hbuf slot t+1; wd[t] into obuf slot t.
// Each is read before being overwritten by the same thread.
// Flat index for (t, b, d) is t*BD + g with g = b*DIMN + d -> fully coalesced.
// ---------------------------------------------------------------------------
__device__ __forceinline__ float fast_sigmoid(float z) {
    return 1.0f / (1.0f + __expf(-z));
}
__device__ __forceinline__ float fast_tanh(float z) {
    // 1 - 2/(e^{2z}+1): safe at both extremes (exp->inf gives 1, exp->0 gives -1)
    return 1.0f - 2.0f / (__expf(2.0f * z) + 1.0f);
}

__global__ __launch_bounds__(64)
void scan_kernel(const float* __restrict__ x, const float* __restrict__ h0,
                 const float* __restrict__ r_h, const float* __restrict__ r_delta,
                 const float* __restrict__ bvec, const float* __restrict__ b_delta,
                 const float* __restrict__ b_gate,
                 float* __restrict__ obuf, float* __restrict__ hbuf) {
    const int g = blockIdx.x * 64 + threadIdx.x;   // 0..32767
    const int d = g & (DIMN - 1);

    const float rh = r_h[d];
    const float rd = r_delta[d];
    const float bb = bvec[d];
    const float bd = b_delta[d];
    const float bg = b_gate[d];

    float h = h0[g];
    hbuf[g] = h;                       // h[0] = h0

    size_t off = (size_t)g;
    // prefetch t = 0
    float wx = hbuf[off + BD];
    float wd = obuf[off];
    float xt = x[off];

    for (int t = 0; t < TT; ++t) {
        const size_t noff = off + BD;
        // prefetch next iteration before this iteration's stores
        const size_t poff = (t < TT - 1) ? noff : off;  // clamp (redundant reload last iter)
        float wxn = hbuf[poff + BD];
        float wdn = obuf[poff];
        float xn  = x[poff];

        float cand  = fast_tanh(rh * h + wx + bb);
        float delta = fast_sigmoid(wd + rd * h + bd);
        h = (1.0f - delta) * h + delta * cand;
        float gg = h + xt + bg;
        float o  = h * (gg * fast_sigmoid(gg));   // h * silu(g)

        obuf[off] = o;
        hbuf[off + BD] = h;

        off = noff; wx = wxn; wd = wdn; xt = xn;
    }
}

// ---------------------------------------------------------------------------
extern "C" void kernel_launch(void* const* d_in, const int* in_sizes, int n_in,
                              void* d_out, int out_size, void* d_ws, size_t ws_size,
                              hipStream_t stream) {
    const float* x       = (const float*)d_in[0];   // [T,B,D]
    const float* h0      = (const float*)d_in[1];   // [B,D]
    const float* U_x     = (const float*)d_in[2];   // [D,R]
    const float* V_x     = (const float*)d_in[3];   // [R,D]
    const float* U_d     = (const float*)d_in[4];   // [D,R]
    const float* V_d     = (const float*)d_in[5];   // [R,D]
    const float* r_h     = (const float*)d_in[6];
    const float* r_delta = (const float*)d_in[7];
    const float* bvec    = (const float*)d_in[8];
    const float* b_delta = (const float*)d_in[9];
    const float* b_gate  = (const float*)d_in[10];

    float* obuf = (float*)d_out;                    // output [T,B,D]
    float* hbuf = obuf + (size_t)TT * BD;           // h [T+1,B,D]
    float* xvd  = (float*)d_ws;                     // [16384, 256]: xv | xd

    const int M = TT * BBATCH;   // 16384

    dim3 blk(256);
    // Phase 1: xv = x @ V_x^T (cols 0..127), xd = x @ V_d^T (cols 128..255)
    gemm_abt<<<dim3(M / 64, RANKN / 64), blk, 0, stream>>>(
        x, V_x, xvd,        M, RANKN, DIMN, DIMN, DIMN, 2 * RANKN);
    gemm_abt<<<dim3(M / 64, RANKN / 64), blk, 0, stream>>>(
        x, V_d, xvd + RANKN, M, RANKN, DIMN, DIMN, DIMN, 2 * RANKN);

    // Phase 2: wx -> hbuf slots t+1; wd -> obuf slots t
    gemm_abt<<<dim3(M / 64, DIMN / 64), blk, 0, stream>>>(
        xvd,         U_x, hbuf + BD, M, DIMN, RANKN, 2 * RANKN, RANKN, DIMN);
    gemm_abt<<<dim3(M / 64, DIMN / 64), blk, 0, stream>>>(
        xvd + RANKN, U_d, obuf,      M, DIMN, RANKN, 2 * RANKN, RANKN, DIMN);

    // Phase 3: elementwise-parallel scan over t
    scan_kernel<<<BD / 64, 64, 0, stream>>>(
        x, h0, r_h, r_delta, bvec, b_delta, b_gate, obuf, hbuf);
}

// Round 2
// 769.842 us; speedup vs baseline: 1.8169x; 1.8169x over previous
//
#include <hip/hip_runtime.h>

#define DIMN 2048
#define RANKN 128
#define TT 1024
#define BBATCH 16
#define BD (BBATCH * DIMN)   // 32768 elements per timestep slice

typedef __attribute__((ext_vector_type(4))) float floatx4;
typedef __attribute__((ext_vector_type(8))) short short8;

// fp32 -> bf16 round-to-nearest-even on raw bits
__device__ __forceinline__ short f2bf(float f) {
    unsigned u = __float_as_uint(f);
    unsigned r = (u + 0x7FFFu + ((u >> 16) & 1u)) >> 16;
    return (short)r;
}

// ---------------------------------------------------------------------------
// bf16 MFMA GEMM: C = A([M,K] fp32, ld=lda) x Bt([N,K] fp32, ld=ldb)^T
// Tile 128x128, BK=32, 256 threads = 4 waves arranged 2x2, 64x64 per wave.
// blockIdx.z in {0,1} selects (A,Bt,C) pointer set -> two GEMMs in one
// dispatch sharing L2/L3 locality on A.
// All dims divide tile sizes (M%128==0, N%128==0, K%32==0) -> no guards.
// LDS rows padded to 40 bf16 (80 B): fragment ds_read_b128 conflict-free.
// ---------------------------------------------------------------------------
__global__ __launch_bounds__(256)
void gemm_mfma(const float* __restrict__ A0, const float* __restrict__ A1,
               const float* __restrict__ B0, const float* __restrict__ B1,
               float* __restrict__ C0, float* __restrict__ C1,
               int K, int lda, int ldb, int ldc) {
    constexpr int PADK = 40;
    __shared__ short As[128 * PADK];
    __shared__ short Bs[128 * PADK];

    const float* A  = blockIdx.z ? A1 : A0;
    const float* Bt = blockIdx.z ? B1 : B0;
    float*       C  = blockIdx.z ? C1 : C0;

    const int m0 = blockIdx.x * 128;
    const int n0 = blockIdx.y * 128;
    const int tid  = threadIdx.x;
    const int wave = tid >> 6;
    const int lane = tid & 63;
    const int lr = lane & 15;        // fragment row/col within 16
    const int q  = lane >> 4;        // quad 0..3
    const int wm = (wave >> 1) * 64; // wave m-offset
    const int wn = (wave & 1) * 64;  // wave n-offset

    floatx4 acc[4][4] = {};

    for (int k0 = 0; k0 < K; k0 += 32) {
        // Stage A and B tiles: 128x32 fp32 each -> bf16 LDS. 1024 float4
        // per tile, 256 threads -> 4 each, coalesced.
        #pragma unroll
        for (int i = 0; i < 4; ++i) {
            int f = tid + i * 256;
            int r = f >> 3;            // 8 float4 per row of 32
            int c = (f & 7) * 4;
            float4 va = *(const float4*)(A + (size_t)(m0 + r) * lda + k0 + c);
            short4 pa = make_short4(f2bf(va.x), f2bf(va.y), f2bf(va.z), f2bf(va.w));
            *(short4*)&As[r * PADK + c] = pa;
            float4 vb = *(const float4*)(Bt + (size_t)(n0 + r) * ldb + k0 + c);
            short4 pb = make_short4(f2bf(vb.x), f2bf(vb.y), f2bf(vb.z), f2bf(vb.w));
            *(short4*)&Bs[r * PADK + c] = pb;
        }
        __syncthreads();

        // Fragment loads: lane holds A[m=lr][k=q*8+j], 8 contiguous bf16.
        short8 af[4], bfr[4];
        #pragma unroll
        for (int i = 0; i < 4; ++i) {
            af[i]  = *(const short8*)&As[(wm + i * 16 + lr) * PADK + q * 8];
            bfr[i] = *(const short8*)&Bs[(wn + i * 16 + lr) * PADK + q * 8];
        }
        #pragma unroll
        for (int i = 0; i < 4; ++i)
            #pragma unroll
            for (int j = 0; j < 4; ++j)
                acc[i][j] = __builtin_amdgcn_mfma_f32_16x16x32_bf16(
                    af[i], bfr[j], acc[i][j], 0, 0, 0);
        __syncthreads();
    }

    // Epilogue: C/D layout col=lane&15, row=(lane>>4)*4+reg (m89-verified).
    #pragma unroll
    for (int i = 0; i < 4; ++i)
        #pragma unroll
        for (int j = 0; j < 4; ++j)
            #pragma unroll
            for (int r = 0; r < 4; ++r) {
                int row = m0 + wm + i * 16 + q * 4 + r;
                int col = n0 + wn + j * 16 + lr;
                C[(size_t)row * ldc + col] = acc[i][j][r];
            }
}

// ---------------------------------------------------------------------------
// Scan: one thread per (b,d); sequential over t; prefetch depth P=8 so each
// thread keeps 24 loads in flight (Little's law: 32768 thr x 96 B = 3.1 MB
// in flight -> ~5-6 TB/s vs the 1.08 TB/s of depth-1).
// wx[t] lives in hbuf slot t+1, wd[t] in obuf slot t (read-before-overwrite,
// same thread, same address -> program order safe).
// ---------------------------------------------------------------------------
__device__ __forceinline__ float fast_sigmoid(float z) {
    return 1.0f / (1.0f + __expf(-z));
}
__device__ __forceinline__ float fast_tanh(float z) {
    return 1.0f - 2.0f / (__expf(2.0f * z) + 1.0f);
}

__global__ __launch_bounds__(64)
void scan_kernel(const float* __restrict__ x, const float* __restrict__ h0,
                 const float* __restrict__ r_h, const float* __restrict__ r_delta,
                 const float* __restrict__ bvec, const float* __restrict__ b_delta,
                 const float* __restrict__ b_gate,
                 float* __restrict__ obuf, float* __restrict__ hbuf) {
    const int g = blockIdx.x * 64 + threadIdx.x;   // 0..32767
    const int d = g & (DIMN - 1);

    const float rh  = r_h[d];
    const float rd  = r_delta[d];
    const float bb  = bvec[d];
    const float bdl = b_delta[d];
    const float bg  = b_gate[d];

    float h = h0[g];
    hbuf[g] = h;                       // h[0] = h0

    constexpr int P = 8;
    float wxb[P], wdb[P], xb[P];
    #pragma unroll
    for (int p = 0; p < P; ++p) {
        size_t o = (size_t)p * BD + g;
        wxb[p] = hbuf[o + BD];
        wdb[p] = obuf[o];
        xb[p]  = x[o];
    }

    // Main loop: t in [0, TT-P), always prefetching t+P (<= TT-1, in bounds).
    for (int t0 = 0; t0 < TT - P; t0 += P) {
        #pragma unroll
        for (int p = 0; p < P; ++p) {
            const int t = t0 + p;
            const size_t off = (size_t)t * BD + g;
            const float wx = wxb[p], wd = wdb[p], xt = xb[p];
            // issue next loads before compute/stores
            const size_t lo = off + (size_t)P * BD;
            wxb[p] = hbuf[lo + BD];
            wdb[p] = obuf[lo];
            xb[p]  = x[lo];

            const float cand  = fast_tanh(rh * h + wx + bb);
            const float delta = fast_sigmoid(wd + rd * h + bdl);
            h = (1.0f - delta) * h + delta * cand;
            const float gg = h + xt + bg;
            obuf[off]      = h * (gg * fast_sigmoid(gg));  // h * silu(g)
            hbuf[off + BD] = h;
        }
    }
    // Tail: last P steps, no prefetch.
    #pragma unroll
    for (int p = 0; p < P; ++p) {
        const int t = TT - P + p;
        const size_t off = (size_t)t * BD + g;
        const float wx = wxb[p], wd = wdb[p], xt = xb[p];
        const float cand  = fast_tanh(rh * h + wx + bb);
        const float delta = fast_sigmoid(wd + rd * h + bdl);
        h = (1.0f - delta) * h + delta * cand;
        const float gg = h + xt + bg;
        obuf[off]      = h * (gg * fast_sigmoid(gg));
        hbuf[off + BD] = h;
    }
}

// ---------------------------------------------------------------------------
extern "C" void kernel_launch(void* const* d_in, const int* in_sizes, int n_in,
                              void* d_out, int out_size, void* d_ws, size_t ws_size,
                              hipStream_t stream) {
    const float* x       = (const float*)d_in[0];   // [T,B,D]
    const float* h0      = (const float*)d_in[1];   // [B,D]
    const float* U_x     = (const float*)d_in[2];   // [D,R]
    const float* V_x     = (const float*)d_in[3];   // [R,D]
    const float* U_d     = (const float*)d_in[4];   // [D,R]
    const float* V_d     = (const float*)d_in[5];   // [R,D]
    const float* r_h     = (const float*)d_in[6];
    const float* r_delta = (const float*)d_in[7];
    const float* bvec    = (const float*)d_in[8];
    const float* b_delta = (const float*)d_in[9];
    const float* b_gate  = (const float*)d_in[10];

    float* obuf = (float*)d_out;                    // output [T,B,D]
    float* hbuf = obuf + (size_t)TT * BD;           // h [T+1,B,D]
    float* xvd  = (float*)d_ws;                     // [16384, 256]: xv | xd

    const int M = TT * BBATCH;   // 16384

    // Phase 1: xv = x @ V_x^T, xd = x @ V_d^T  (M=16384, N=128, K=2048)
    dim3 g1(M / 128, 1, 2);
    gemm_mfma<<<g1, 256, 0, stream>>>(
        x, x, V_x, V_d, xvd, xvd + RANKN,
        DIMN, DIMN, DIMN, 2 * RANKN);

    // Phase 2: wx = xv @ U_x^T -> hbuf slots 1..T ; wd = xd @ U_d^T -> obuf
    // (M=16384, N=2048, K=128)
    dim3 g2(M / 128, DIMN / 128, 2);
    gemm_mfma<<<g2, 256, 0, stream>>>(
        xvd, xvd + RANKN, U_x, U_d, hbuf + BD, obuf,
        RANKN, 2 * RANKN, RANKN, DIMN);

    // Phase 3: elementwise-parallel scan over t
    scan_kernel<<<BD / 64, 64, 0, stream>>>(
        x, h0, r_h, r_delta, bvec, b_delta, b_gate, obuf, hbuf);
}